// Round 7
// baseline (69.718 us; speedup 1.0000x reference)
//
#include <hip/hip_runtime.h>

// Problem: out[b,h,w,i,k] = inputs[b,h,w,i] * u[i,k],
//          u[i,k] = beta[i,k]^2 / sum_k beta[i,k]^2
// Shapes: inputs (4,256,256,32) f32, beta (32,8) f32, out (...,32,8) f32.
// Memory-bound: 256 MiB write + 32 MiB read. Mandatory traffic 302 MB.
//
// Round-6 (60.8 us, 4.97 TB/s): reads and writes interleaved every 4 KB per
// wave, only 4 loads in flight. Round-7: trip count is exactly 32 ->
// FULLY unroll. Phase 1 issues all 32 global loads (pure read burst,
// 32-deep MLP); phase 2 drains them into 32 nt-stores (compiler emits
// descending vmcnt(N) waits -> stores start as soon as first load lands).
// Statically-indexed x[] stays in registers (unrolled loops, rule #20).

#define DIMD 32
#define DIMK 8
#define ITERS 32

typedef float f32x4 __attribute__((ext_vector_type(4)));

__global__ __launch_bounds__(256) void mass_proto_kernel(
    const float* __restrict__ inputs,
    const float* __restrict__ beta,
    float* __restrict__ out,
    int n4)  // number of float4 output chunks = out_size/4
{
    __shared__ float bsq[DIMD * DIMK];
    __shared__ float u[DIMD * DIMK];

    // --- compute u (256 threads, one element each) ---
    const int t = threadIdx.x;              // 0..255
    float b = beta[t];
    bsq[t] = b * b;
    __syncthreads();
    const int row = t >> 3;                 // feature index i
    float s = 0.f;
#pragma unroll
    for (int j = 0; j < DIMK; ++j) s += bsq[row * DIMK + j];
    u[t] = bsq[t] / s;
    __syncthreads();

    const f32x4* __restrict__ u4 = reinterpret_cast<const f32x4*>(u);
    f32x4* __restrict__ out4 = reinterpret_cast<f32x4*>(out);

    // stride % 64 == 0 -> u4[(idx + j*stride)&63] is loop-invariant.
    const f32x4 uu = u4[t & 63];

    const int idx = blockIdx.x * blockDim.x + threadIdx.x;
    const int stride = gridDim.x * blockDim.x;

    if (idx + (ITERS - 1) * stride < n4) {
        // fast path (always taken for the bench shape: n4 == ITERS*stride)
        float x[ITERS];
#pragma unroll
        for (int j = 0; j < ITERS; ++j)
            x[j] = inputs[(idx + j * stride) >> 1];   // 32 loads in flight
#pragma unroll
        for (int j = 0; j < ITERS; ++j)
            __builtin_nontemporal_store(x[j] * uu, &out4[idx + j * stride]);
    } else {
        for (int i = idx; i < n4; i += stride)
            __builtin_nontemporal_store(inputs[i >> 1] * uu, &out4[i]);
    }
}

extern "C" void kernel_launch(void* const* d_in, const int* in_sizes, int n_in,
                              void* d_out, int out_size, void* d_ws, size_t ws_size,
                              hipStream_t stream) {
    const float* inputs = (const float*)d_in[0];  // (4,256,256,32)
    const float* beta   = (const float*)d_in[1];  // (32,8)
    float* out = (float*)d_out;                   // (4,256,256,32,8)

    const int n4 = out_size / 4;                  // 16,777,216 float4s
    const int threads = 256;
    const int blocks = 2048;                      // n4 / (threads*ITERS) blocks' stride

    mass_proto_kernel<<<blocks, threads, 0, stream>>>(inputs, beta, out, n4);
}

// Round 8
// 68.511 us; speedup vs baseline: 1.0176x; 1.0176x over previous
//
#include <hip/hip_runtime.h>

// Problem: out[b,h,w,i,k] = inputs[b,h,w,i] * u[i,k],
//          u[i,k] = beta[i,k]^2 / sum_k beta[i,k]^2
// Shapes: inputs (4,256,256,32) f32, beta (32,8) f32, out (...,32,8) f32.
// Memory-bound: 256 MiB write + 32 MiB read. Mandatory traffic 302 MB.
//
// History: r6 x4-unroll grid-stride = 60.8us (4.97 TB/s). r7 full x32
// unroll = 69.7us REGRESSION: x[32] pushed VGPR past 64 -> occupancy
// halved (4 waves/SIMD). Streaming kernels live on TLP.
// Round-8: unroll x8 — 8 loads in flight per wave (2x the latency
// coverage of r6) while keeping VGPR <= 64 (8 waves/SIMD, 32 waves/CU).

#define DIMD 32
#define DIMK 8
#define UNROLL 8

typedef float f32x4 __attribute__((ext_vector_type(4)));

__global__ __launch_bounds__(256) void mass_proto_kernel(
    const float* __restrict__ inputs,
    const float* __restrict__ beta,
    float* __restrict__ out,
    int n4)  // number of float4 output chunks = out_size/4
{
    __shared__ float bsq[DIMD * DIMK];
    __shared__ float u[DIMD * DIMK];

    // --- compute u (256 threads, one element each) ---
    const int t = threadIdx.x;              // 0..255
    float b = beta[t];
    bsq[t] = b * b;
    __syncthreads();
    const int row = t >> 3;                 // feature index i
    float s = 0.f;
#pragma unroll
    for (int j = 0; j < DIMK; ++j) s += bsq[row * DIMK + j];
    u[t] = bsq[t] / s;
    __syncthreads();

    const f32x4* __restrict__ u4 = reinterpret_cast<const f32x4*>(u);
    f32x4* __restrict__ out4 = reinterpret_cast<f32x4*>(out);

    // stride % 64 == 0 -> u4[(idx + j*stride)&63] is loop-invariant.
    const f32x4 uu = u4[t & 63];

    int idx = blockIdx.x * blockDim.x + threadIdx.x;
    const int stride = gridDim.x * blockDim.x;

    // --- main loop: x8 unrolled, loads batched ahead of stores ---
    for (; idx + (UNROLL - 1) * stride < n4; idx += UNROLL * stride) {
        float x[UNROLL];
#pragma unroll
        for (int j = 0; j < UNROLL; ++j)
            x[j] = inputs[(idx + j * stride) >> 1];   // 8 loads in flight
#pragma unroll
        for (int j = 0; j < UNROLL; ++j)
            __builtin_nontemporal_store(x[j] * uu, &out4[idx + j * stride]);
    }
    // tail (not taken for the bench shape: n4/stride == 32, 32%8 == 0)
    for (; idx < n4; idx += stride)
        __builtin_nontemporal_store(inputs[idx >> 1] * uu, &out4[idx]);
}

extern "C" void kernel_launch(void* const* d_in, const int* in_sizes, int n_in,
                              void* d_out, int out_size, void* d_ws, size_t ws_size,
                              hipStream_t stream) {
    const float* inputs = (const float*)d_in[0];  // (4,256,256,32)
    const float* beta   = (const float*)d_in[1];  // (32,8)
    float* out = (float*)d_out;                   // (4,256,256,32,8)

    const int n4 = out_size / 4;                  // 16,777,216 float4s
    const int threads = 256;
    const int blocks = 2048;                      // 8 blocks/CU, 32 waves/CU

    mass_proto_kernel<<<blocks, threads, 0, stream>>>(inputs, beta, out, n4);
}

// Round 9
// 68.082 us; speedup vs baseline: 1.0240x; 1.0063x over previous
//
#include <hip/hip_runtime.h>

// Problem: out[b,h,w,i,k] = inputs[b,h,w,i] * u[i,k],
//          u[i,k] = beta[i,k]^2 / sum_k beta[i,k]^2
// Shapes: inputs (4,256,256,32) f32, beta (32,8) f32, out (...,32,8) f32.
// Memory-bound: 256 MiB write + 33.5 MiB read.
//
// History: r6 x4 grid-stride + nt = 60.8us (4.97 TB/s). r7 x32 unroll =
// 69.7 (VGPR>64, occupancy halved). r8 x8 = 68.5. Per-wave MLP is not the
// lever. Pure-write fill kernels on this chip: 6.9 TB/s. Diagnosis: the
// fine-grained read/write interleave (1:8) pays DRAM bus-turnaround tax,
// and vmcnt FIFO couples compute to store drain.
// Round-9: PHASE-SEPARATE. Each block stages its whole 16 KiB input slice
// into LDS first (coalesced float4), one barrier, then a pure nt-store
// stream with operands from LDS (lgkmcnt — decoupled from store vmcnt).
// Machine-wide: ~5us read burst, then pure writes. 18 KiB LDS -> 8
// blocks/CU, full occupancy.

#define DIMD 32
#define DIMK 8
#define TRIPS 32   // chunks per thread = n4 / stride

typedef float f32x4 __attribute__((ext_vector_type(4)));

__global__ __launch_bounds__(256) void mass_proto_kernel(
    const float* __restrict__ inputs,
    const float* __restrict__ beta,
    float* __restrict__ out,
    int n4,       // total float4 output chunks = out_size/4
    int nelem4)   // total input float4s = (out_size/8)/4
{
    __shared__ __align__(16) float u[DIMD * DIMK];      // 1 KiB
    __shared__ float bsq[DIMD * DIMK];                  // 1 KiB
    __shared__ __align__(16) float xin[TRIPS * 128];    // 16 KiB staged input

    const int t = threadIdx.x;                 // 0..255
    const int stride  = gridDim.x * blockDim.x;  // chunk stride per trip
    const int estride4 = stride >> 3;            // float4 elements per trip

    // ---- issue the staging loads FIRST (latency overlaps u-compute) ----
    const f32x4* __restrict__ in4 = reinterpret_cast<const f32x4*>(inputs);
    f32x4 v0, v1, v2, v3;
    {
        const int base = blockIdx.x * 32 + (t & 31);
        const int j0 = (0 * 256 + t) >> 5;   // = t>>5
        const int j1 = (1 * 256 + t) >> 5;
        const int j2 = (2 * 256 + t) >> 5;
        const int j3 = (3 * 256 + t) >> 5;
        int g0 = base + j0 * estride4;
        int g1 = base + j1 * estride4;
        int g2 = base + j2 * estride4;
        int g3 = base + j3 * estride4;
        v0 = (g0 < nelem4) ? in4[g0] : (f32x4)0.f;
        v1 = (g1 < nelem4) ? in4[g1] : (f32x4)0.f;
        v2 = (g2 < nelem4) ? in4[g2] : (f32x4)0.f;
        v3 = (g3 < nelem4) ? in4[g3] : (f32x4)0.f;
    }

    // ---- compute u (256 threads, one element each) ----
    float b = beta[t];
    bsq[t] = b * b;
    __syncthreads();
    const int row = t >> 3;                    // feature index i
    float s = 0.f;
#pragma unroll
    for (int j = 0; j < DIMK; ++j) s += bsq[row * DIMK + j];
    u[t] = bsq[t] / s;

    // ---- park staged inputs in LDS ----
    f32x4* xin4 = reinterpret_cast<f32x4*>(xin);
    xin4[0 * 256 + t] = v0;
    xin4[1 * 256 + t] = v1;
    xin4[2 * 256 + t] = v2;
    xin4[3 * 256 + t] = v3;
    __syncthreads();                           // u and xin both ready

    // ---- pure write stream: operands from LDS, nt stores to HBM ----
    const f32x4* __restrict__ u4 = reinterpret_cast<const f32x4*>(u);
    const f32x4 uu = u4[t & 63];               // loop-invariant (stride%64==0)
    f32x4* __restrict__ out4 = reinterpret_cast<f32x4*>(out);

    const int idx = blockIdx.x * blockDim.x + t;
    const int th = t >> 1;                     // LDS operand slot (pair-broadcast)
#pragma unroll 4
    for (int j = 0; j < TRIPS; ++j) {
        const int c = idx + j * stride;
        if (c < n4) {
            const float x = xin[j * 128 + th];
            __builtin_nontemporal_store(x * uu, &out4[c]);
        }
    }
}

extern "C" void kernel_launch(void* const* d_in, const int* in_sizes, int n_in,
                              void* d_out, int out_size, void* d_ws, size_t ws_size,
                              hipStream_t stream) {
    const float* inputs = (const float*)d_in[0];  // (4,256,256,32)
    const float* beta   = (const float*)d_in[1];  // (32,8)
    float* out = (float*)d_out;                   // (4,256,256,32,8)

    const int n4 = out_size / 4;                  // 16,777,216 float4 chunks
    const int threads = 256;
    const int blocks = (n4 + threads * TRIPS - 1) / (threads * TRIPS);  // 2048
    const int nelem4 = (out_size / DIMK) / 4;     // input float4 count

    mass_proto_kernel<<<blocks, threads, 0, stream>>>(inputs, beta, out, n4, nelem4);
}